// Round 1
// baseline (677.837 us; speedup 1.0000x reference)
//
#include <hip/hip_runtime.h>
#include <hip/hip_bf16.h>
#include <stdint.h>

typedef __bf16 bf16;
typedef float f32x4 __attribute__((ext_vector_type(4)));
typedef bf16 bf16x4 __attribute__((ext_vector_type(4)));
typedef bf16 bf16x8 __attribute__((ext_vector_type(8)));

#define DEV __device__ __forceinline__

union FragU { bf16x4 h[2]; bf16x8 v; };

DEV void gload16(const void* g, void* l) {
  __builtin_amdgcn_global_load_lds((const __attribute__((address_space(1))) void*)g,
                                   (__attribute__((address_space(3))) void*)l, 16, 0, 0);
}

DEV f32x4 mfma16(bf16x8 a, bf16x8 b, f32x4 c) {
  return __builtin_amdgcn_mfma_f32_16x16x32_bf16(a, b, c, 0, 0, 0);
}

static constexpr int Bn = 4, Sn = 2048, Hn = 16, Dn = 128, En = 2048, Mn = 8192;

// ---------------- fp32 -> bf16 elementwise (X) ----------------
__global__ void cvt_x(const float* __restrict__ in, bf16* __restrict__ out, int n8) {
  int i = blockIdx.x * blockDim.x + threadIdx.x;
  int stride = gridDim.x * blockDim.x;
  for (int idx = i; idx < n8; idx += stride) {
    const float4* p = (const float4*)(in + (size_t)idx * 8);
    float4 a = p[0], b = p[1];
    bf16x8 o;
    o[0]=(bf16)a.x; o[1]=(bf16)a.y; o[2]=(bf16)a.z; o[3]=(bf16)a.w;
    o[4]=(bf16)b.x; o[5]=(bf16)b.y; o[6]=(bf16)b.z; o[7]=(bf16)b.w;
    *(bf16x8*)(out + (size_t)idx * 8) = o;
  }
}

// ---------------- W [K][N] fp32 -> Wt [N][K] bf16 (2048x2048) ----------------
__global__ void wtrans(const float* __restrict__ W, bf16* __restrict__ Wt) {
  __shared__ bf16 t[64][65];
  int tx = threadIdx.x & 15, ty = threadIdx.x >> 4;
  int c0 = blockIdx.x * 64, r0 = blockIdx.y * 64;
  #pragma unroll
  for (int i = 0; i < 4; ++i) {
    int r = i * 16 + ty;
    float4 v = *(const float4*)&W[(size_t)(r0 + r) * En + c0 + tx * 4];
    t[r][tx*4+0] = (bf16)v.x; t[r][tx*4+1] = (bf16)v.y;
    t[r][tx*4+2] = (bf16)v.z; t[r][tx*4+3] = (bf16)v.w;
  }
  __syncthreads();
  #pragma unroll
  for (int i = 0; i < 4; ++i) {
    int c = i * 16 + ty;
    bf16x4 o;
    #pragma unroll
    for (int j = 0; j < 4; ++j) o[j] = t[tx*4+j][c];
    *(bf16x4*)&Wt[(size_t)(c0 + c) * En + r0 + tx * 4] = o;
  }
}

// ---------------- V [bh][S][D] bf16 -> Vt [bh][D][S] bf16 ----------------
__global__ void vtrans(const bf16* __restrict__ V, bf16* __restrict__ Vt) {
  __shared__ bf16 t[64][65];
  int tx = threadIdx.x & 15, ty = threadIdx.x >> 4;
  int s0 = blockIdx.x * 64, d0 = blockIdx.y * 64, bh = blockIdx.z;
  const bf16* Vi = V + (size_t)bh * Sn * Dn;
  bf16* Vo = Vt + (size_t)bh * Sn * Dn;
  #pragma unroll
  for (int i = 0; i < 4; ++i) {
    int r = i * 16 + ty;
    bf16x4 v = *(const bf16x4*)&Vi[(size_t)(s0 + r) * Dn + d0 + tx * 4];
    #pragma unroll
    for (int j = 0; j < 4; ++j) t[r][tx*4+j] = v[j];
  }
  __syncthreads();
  #pragma unroll
  for (int i = 0; i < 4; ++i) {
    int dd = i * 16 + ty;
    bf16x4 o;
    #pragma unroll
    for (int j = 0; j < 4; ++j) o[j] = t[tx*4+j][dd];
    *(bf16x4*)&Vo[(size_t)(d0 + dd) * Sn + s0 + tx * 4] = o;
  }
}

// ---------------- GEMM: C[M][N] = A[M][K] @ Bt[N][K]^T + bias ----------------
// 128x128 tile, BK=64, 4 waves (2x2), global_load_lds staging, XOR-16B swizzle.
// OUT_MODE 0: bf16 written in [B][H][S][D] layout; OUT_MODE 1: fp32 row-major.
template<int OUT_MODE>
__global__ __launch_bounds__(256, 2) void gemm_bt(
    const bf16* __restrict__ A, const bf16* __restrict__ Bt,
    const float* __restrict__ bias, void* __restrict__ Cout,
    int M, int N, int K)
{
  __shared__ __align__(16) uint8_t smem[32768];
  uint8_t* As = smem;
  uint8_t* Bs = smem + 16384;
  const int tid = threadIdx.x;
  const int lane = tid & 63, w = tid >> 6;
  const int wm = w >> 1, wn = w & 1;
  const int g = lane >> 4, lr = lane & 15;
  const int mbase = blockIdx.y * 128, nbase = blockIdx.x * 128;

  f32x4 acc[4][4] = {};

  const int nkt = K >> 6;
  for (int kt = 0; kt < nkt; ++kt) {
    const bf16* Ag = A + (size_t)mbase * K + kt * 64;
    const bf16* Bg = Bt + (size_t)nbase * K + kt * 64;
    #pragma unroll
    for (int it = 0; it < 4; ++it) {
      int cl = it * 256 + tid;
      int row = cl >> 3, cs = cl & 7;
      int cg = cs ^ (row & 7);
      int ldsoff = (it * 256 + (tid & ~63)) * 16;
      gload16(Ag + (size_t)row * K + cg * 8, As + ldsoff);
      gload16(Bg + (size_t)row * K + cg * 8, Bs + ldsoff);
    }
    __syncthreads();
    #pragma unroll
    for (int ks = 0; ks < 2; ++ks) {
      FragU af[4], bfm[4];
      int c0 = ks * 64 + g * 8;
      #pragma unroll
      for (int mf = 0; mf < 4; ++mf) {
        int row = wm * 64 + mf * 16 + lr;
        int sw = (row & 7) << 4;
        af[mf].h[0] = *(const bf16x4*)(As + row * 128 + (c0 ^ sw));
        af[mf].h[1] = *(const bf16x4*)(As + row * 128 + ((c0 + 32) ^ sw));
      }
      #pragma unroll
      for (int nf = 0; nf < 4; ++nf) {
        int row = wn * 64 + nf * 16 + lr;
        int sw = (row & 7) << 4;
        bfm[nf].h[0] = *(const bf16x4*)(Bs + row * 128 + (c0 ^ sw));
        bfm[nf].h[1] = *(const bf16x4*)(Bs + row * 128 + ((c0 + 32) ^ sw));
      }
      #pragma unroll
      for (int mf = 0; mf < 4; ++mf)
        #pragma unroll
        for (int nf = 0; nf < 4; ++nf)
          acc[mf][nf] = mfma16(af[mf].v, bfm[nf].v, acc[mf][nf]);
    }
    __syncthreads();
  }

  #pragma unroll
  for (int mf = 0; mf < 4; ++mf) {
    #pragma unroll
    for (int nf = 0; nf < 4; ++nf) {
      int n = nbase + wn * 64 + nf * 16 + lr;
      float bv = bias[n];
      #pragma unroll
      for (int r = 0; r < 4; ++r) {
        int m = mbase + wm * 64 + mf * 16 + g * 4 + r;
        float val = acc[mf][nf][r] + bv;
        if constexpr (OUT_MODE == 0) {
          int b = m >> 11, s = m & 2047, h = n >> 7, d = n & 127;
          ((bf16*)Cout)[((size_t)(b * Hn + h) * Sn + s) * Dn + d] = (bf16)val;
        } else {
          ((float*)Cout)[(size_t)m * N + n] = val;
        }
      }
    }
  }
}

// ---------------- Flash attention ----------------
// Block: 128 q-rows of one (b,h); 4 waves x 32 q-rows. KVBLK=64.
// Swapped QK^T (mfma(K,Q) -> S^T) so P stays in-register for PV's A operand.
__global__ __launch_bounds__(256, 2) void attn(
    const bf16* __restrict__ Q, const bf16* __restrict__ K,
    const bf16* __restrict__ Vt, bf16* __restrict__ O)
{
  __shared__ __align__(16) uint8_t smem[32768];
  const int tid = threadIdx.x, lane = tid & 63, w = tid >> 6;
  const int g = lane >> 4, lr = lane & 15;
  const int bh = blockIdx.y;
  const int q0 = blockIdx.x * 128;
  const size_t hoff = (size_t)bh * Sn * Dn;
  const bf16* Qh = Q + hoff;
  const bf16* Kh = K + hoff;
  const bf16* Vh = Vt + hoff;   // [D][S]
  const float scale = 0.08838834764831845f;

  // stage Q tile [128 rows][256B], XOR-swizzled
  #pragma unroll
  for (int it = 0; it < 8; ++it) {
    int cl = it * 256 + tid;
    int row = cl >> 4, cs = cl & 15;
    int cg = cs ^ (row & 7);
    gload16(Qh + (size_t)(q0 + row) * Dn + cg * 8, smem + (it * 256 + (tid & ~63)) * 16);
  }
  __syncthreads();

  // hoist Q fragments (B operand): per wave rows [w*32, w*32+32)
  FragU qf[2][4];
  #pragma unroll
  for (int nf = 0; nf < 2; ++nf)
    #pragma unroll
    for (int ks = 0; ks < 4; ++ks) {
      int row = w * 32 + nf * 16 + lr;
      int sw = (row & 7) << 4;
      int c0 = ks * 64 + g * 8;
      qf[nf][ks].h[0] = *(const bf16x4*)(smem + row * 256 + (c0 ^ sw));
      qf[nf][ks].h[1] = *(const bf16x4*)(smem + row * 256 + ((c0 + 32) ^ sw));
    }
  __syncthreads();

  uint8_t* Ks = smem;           // [64 kv][256B]
  uint8_t* Vs = smem + 16384;   // [128 d][128B]
  f32x4 o[2][8] = {};
  float mrun[2] = { -__builtin_inff(), -__builtin_inff() };
  float lrun[2] = { 0.f, 0.f };

  for (int kv = 0; kv < Sn; kv += 64) {
    #pragma unroll
    for (int it = 0; it < 4; ++it) {
      int cl = it * 256 + tid;
      int ldsoff = (it * 256 + (tid & ~63)) * 16;
      { int row = cl >> 4, cs = cl & 15; int cg = cs ^ (row & 7);
        gload16(Kh + (size_t)(kv + row) * Dn + cg * 8, Ks + ldsoff); }
      { int row = cl >> 3, cs = cl & 7; int cg = cs ^ (row & 7);
        gload16(Vh + (size_t)row * Sn + kv + cg * 8, Vs + ldsoff); }
    }
    __syncthreads();

    // QK^T (swapped): sfr[nf][mf] = S^T fragment, row=kv(4g+reg), col=q(lr)
    f32x4 sfr[2][4] = {};
    #pragma unroll
    for (int ks = 0; ks < 4; ++ks) {
      FragU kf[4];
      int c0 = ks * 64 + g * 8;
      #pragma unroll
      for (int mf = 0; mf < 4; ++mf) {
        int row = mf * 16 + lr;
        int sw = (row & 7) << 4;
        kf[mf].h[0] = *(const bf16x4*)(Ks + row * 256 + (c0 ^ sw));
        kf[mf].h[1] = *(const bf16x4*)(Ks + row * 256 + ((c0 + 32) ^ sw));
      }
      #pragma unroll
      for (int mf = 0; mf < 4; ++mf)
        #pragma unroll
        for (int nf = 0; nf < 2; ++nf)
          sfr[nf][mf] = mfma16(kf[mf].v, qf[nf][ks].v, sfr[nf][mf]);
    }

    // online softmax (per lane: q = lr, kv set = {16*mf + 4*g + r})
    FragU pa[2][2];
    #pragma unroll
    for (int nf = 0; nf < 2; ++nf) {
      float mx = -__builtin_inff();
      #pragma unroll
      for (int mf = 0; mf < 4; ++mf)
        #pragma unroll
        for (int r = 0; r < 4; ++r) {
          float v = sfr[nf][mf][r] * scale;
          sfr[nf][mf][r] = v;
          mx = fmaxf(mx, v);
        }
      mx = fmaxf(mx, __shfl_xor(mx, 16));
      mx = fmaxf(mx, __shfl_xor(mx, 32));
      float mnew = fmaxf(mrun[nf], mx);
      float fsc = __expf(mrun[nf] - mnew);
      mrun[nf] = mnew;
      float ps = 0.f;
      #pragma unroll
      for (int mf = 0; mf < 4; ++mf)
        #pragma unroll
        for (int r = 0; r < 4; ++r) {
          float pv = __expf(sfr[nf][mf][r] - mnew);
          sfr[nf][mf][r] = pv;
          ps += pv;
        }
      ps += __shfl_xor(ps, 16);
      ps += __shfl_xor(ps, 32);
      lrun[nf] = lrun[nf] * fsc + ps;
      // P -> bf16 A-frags: slot i <- kv 32ks+4g+i (mf=2ks), slot i+4 <- +16 (mf=2ks+1)
      #pragma unroll
      for (int ks = 0; ks < 2; ++ks) {
        bf16x8 t;
        #pragma unroll
        for (int i = 0; i < 4; ++i) {
          t[i]     = (bf16)sfr[nf][2 * ks][i];
          t[i + 4] = (bf16)sfr[nf][2 * ks + 1][i];
        }
        pa[nf][ks].v = t;
      }
      // rescale O accumulators (factor indexed by O-row q = 4g+r)
      f32x4 fv;
      #pragma unroll
      for (int r = 0; r < 4; ++r) fv[r] = __shfl(fsc, g * 4 + r);
      #pragma unroll
      for (int df = 0; df < 8; ++df)
        #pragma unroll
        for (int r = 0; r < 4; ++r) o[nf][df][r] *= fv[r];
    }

    // PV: o[q][d] += P @ V  (A=pa in-register, B=Vt tile, A-style read)
    #pragma unroll
    for (int ks = 0; ks < 2; ++ks) {
      int c0 = ks * 64 + g * 8;
      #pragma unroll
      for (int df = 0; df < 8; ++df) {
        FragU vf;
        int row = df * 16 + lr;
        int sw = (row & 7) << 4;
        vf.h[0] = *(const bf16x4*)(Vs + row * 128 + (c0 ^ sw));
        vf.h[1] = *(const bf16x4*)(Vs + row * 128 + ((c0 + 32) ^ sw));
        #pragma unroll
        for (int nf = 0; nf < 2; ++nf)
          o[nf][df] = mfma16(pa[nf][ks].v, vf.v, o[nf][df]);
      }
    }
    __syncthreads();
  }

  // finalize: divide by l, write bf16 [M][E] with col = h*128+d
  const int b = bh >> 4, h = bh & 15;
  #pragma unroll
  for (int nf = 0; nf < 2; ++nf) {
    float inv = 1.f / lrun[nf];
    f32x4 iv;
    #pragma unroll
    for (int r = 0; r < 4; ++r) iv[r] = __shfl(inv, g * 4 + r);
    #pragma unroll
    for (int df = 0; df < 8; ++df) {
      #pragma unroll
      for (int r = 0; r < 4; ++r) {
        int qrow = q0 + w * 32 + nf * 16 + g * 4 + r;
        int d = df * 16 + lr;
        size_t m = (size_t)b * Sn + qrow;
        O[m * En + h * Dn + d] = (bf16)(o[nf][df][r] * iv[r]);
      }
    }
  }
}

// ---------------- host ----------------
extern "C" void kernel_launch(void* const* d_in, const int* in_sizes, int n_in,
                              void* d_out, int out_size, void* d_ws, size_t ws_size,
                              hipStream_t stream) {
  const float* X  = (const float*)d_in[0];
  const float* Wq = (const float*)d_in[1];
  const float* bq = (const float*)d_in[2];
  const float* Wk = (const float*)d_in[3];
  const float* bk = (const float*)d_in[4];
  const float* Wv = (const float*)d_in[5];
  const float* bv = (const float*)d_in[6];
  const float* Wo = (const float*)d_in[7];
  const float* bo = (const float*)d_in[8];

  bf16* ws = (bf16*)d_ws;
  const size_t szE = (size_t)Mn * En;      // 16.78M elems
  const size_t szW = (size_t)En * En;      // 4.19M elems
  bf16* Xb  = ws;
  bf16* Wqt = Xb + szE;
  bf16* Wkt = Wqt + szW;
  bf16* Wvt = Wkt + szW;
  bf16* Wot = Wvt + szW;
  bf16* Qb  = Wot + szW;
  bf16* Kb  = Qb + szE;
  bf16* Vb  = Kb + szE;
  bf16* Vtp = Vb + szE;
  bf16* AO  = Vb;   // alias: V consumed by vtrans before attn writes AO

  cvt_x<<<2048, 256, 0, stream>>>(X, Xb, (int)(szE / 8));
  wtrans<<<dim3(32, 32), 256, 0, stream>>>(Wq, Wqt);
  wtrans<<<dim3(32, 32), 256, 0, stream>>>(Wk, Wkt);
  wtrans<<<dim3(32, 32), 256, 0, stream>>>(Wv, Wvt);
  wtrans<<<dim3(32, 32), 256, 0, stream>>>(Wo, Wot);
  gemm_bt<0><<<dim3(16, 64), 256, 0, stream>>>(Xb, Wqt, bq, Qb, Mn, En, En);
  gemm_bt<0><<<dim3(16, 64), 256, 0, stream>>>(Xb, Wkt, bk, Kb, Mn, En, En);
  gemm_bt<0><<<dim3(16, 64), 256, 0, stream>>>(Xb, Wvt, bv, Vb, Mn, En, En);
  vtrans<<<dim3(32, 2, 64), 256, 0, stream>>>(Vb, Vtp);
  attn<<<dim3(16, 64), 256, 0, stream>>>(Qb, Kb, Vtp, AO);
  gemm_bt<1><<<dim3(16, 64), 256, 0, stream>>>(AO, Wot, bo, d_out, Mn, En, En);
}

// Round 3
// 509.279 us; speedup vs baseline: 1.3310x; 1.3310x over previous
//
#include <hip/hip_runtime.h>
#include <hip/hip_bf16.h>
#include <stdint.h>

typedef __bf16 bf16;
typedef float f32x4 __attribute__((ext_vector_type(4)));
typedef bf16 bf16x4 __attribute__((ext_vector_type(4)));
typedef bf16 bf16x8 __attribute__((ext_vector_type(8)));

#define DEV __device__ __forceinline__

DEV void gload16(const void* g, void* l) {
  __builtin_amdgcn_global_load_lds((const __attribute__((address_space(1))) void*)g,
                                   (__attribute__((address_space(3))) void*)l, 16, 0, 0);
}

DEV f32x4 mfma16(bf16x8 a, bf16x8 b, f32x4 c) {
  return __builtin_amdgcn_mfma_f32_16x16x32_bf16(a, b, c, 0, 0, 0);
}

#if __has_builtin(__builtin_amdgcn_exp2f)
DEV float EXP2F(float x) { return __builtin_amdgcn_exp2f(x); }
#else
DEV float EXP2F(float x) { return exp2f(x); }
#endif

static constexpr int Bn = 4, Sn = 2048, Hn = 16, Dn = 128, En = 2048, Mn = 8192;

// ---------------- fp32 -> bf16 elementwise (X) ----------------
__global__ void cvt_x(const float* __restrict__ in, bf16* __restrict__ out, int n8) {
  int i = blockIdx.x * blockDim.x + threadIdx.x;
  int stride = gridDim.x * blockDim.x;
  for (int idx = i; idx < n8; idx += stride) {
    const float4* p = (const float4*)(in + (size_t)idx * 8);
    float4 a = p[0], b = p[1];
    bf16x8 o;
    o[0]=(bf16)a.x; o[1]=(bf16)a.y; o[2]=(bf16)a.z; o[3]=(bf16)a.w;
    o[4]=(bf16)b.x; o[5]=(bf16)b.y; o[6]=(bf16)b.z; o[7]=(bf16)b.w;
    *(bf16x8*)(out + (size_t)idx * 8) = o;
  }
}

// ---------------- W [K][N] fp32 -> Wt [N][K] bf16 (2048x2048) ----------------
__global__ void wtrans(const float* __restrict__ W, bf16* __restrict__ Wt) {
  __shared__ bf16 t[64][65];
  int tx = threadIdx.x & 15, ty = threadIdx.x >> 4;
  int c0 = blockIdx.x * 64, r0 = blockIdx.y * 64;
  #pragma unroll
  for (int i = 0; i < 4; ++i) {
    int r = i * 16 + ty;
    float4 v = *(const float4*)&W[(size_t)(r0 + r) * En + c0 + tx * 4];
    t[r][tx*4+0] = (bf16)v.x; t[r][tx*4+1] = (bf16)v.y;
    t[r][tx*4+2] = (bf16)v.z; t[r][tx*4+3] = (bf16)v.w;
  }
  __syncthreads();
  #pragma unroll
  for (int i = 0; i < 4; ++i) {
    int c = i * 16 + ty;
    bf16x4 o;
    #pragma unroll
    for (int j = 0; j < 4; ++j) o[j] = t[tx*4+j][c];
    *(bf16x4*)&Wt[(size_t)(c0 + c) * En + r0 + tx * 4] = o;
  }
}

// ---------------- V [bh][S][D] bf16 -> Vt [bh][D][S] bf16 ----------------
__global__ void vtrans(const bf16* __restrict__ V, bf16* __restrict__ Vt) {
  __shared__ bf16 t[64][65];
  int tx = threadIdx.x & 15, ty = threadIdx.x >> 4;
  int s0 = blockIdx.x * 64, d0 = blockIdx.y * 64, bh = blockIdx.z;
  const bf16* Vi = V + (size_t)bh * Sn * Dn;
  bf16* Vo = Vt + (size_t)bh * Sn * Dn;
  #pragma unroll
  for (int i = 0; i < 4; ++i) {
    int r = i * 16 + ty;
    bf16x4 v = *(const bf16x4*)&Vi[(size_t)(s0 + r) * Dn + d0 + tx * 4];
    #pragma unroll
    for (int j = 0; j < 4; ++j) t[r][tx*4+j] = v[j];
  }
  __syncthreads();
  #pragma unroll
  for (int i = 0; i < 4; ++i) {
    int dd = i * 16 + ty;
    bf16x4 o;
    #pragma unroll
    for (int j = 0; j < 4; ++j) o[j] = t[tx*4+j][dd];
    *(bf16x4*)&Vo[(size_t)(d0 + dd) * Sn + s0 + tx * 4] = o;
  }
}

// ---------------- GEMM: C[M][N] = A[M][K] @ Bt[N][K]^T + bias ----------------
// 128x128 tile, BK=64, 4 waves (2x2). b128 chunk-XOR frag reads.
template<int OUT_MODE>
__global__ __launch_bounds__(256, 2) void gemm_bt(
    const bf16* __restrict__ A, const bf16* __restrict__ Bt,
    const float* __restrict__ bias, void* __restrict__ Cout,
    int M, int N, int K)
{
  __shared__ __align__(16) uint8_t smem[32768];
  uint8_t* As = smem;
  uint8_t* Bs = smem + 16384;
  const int tid = threadIdx.x;
  const int lane = tid & 63, w = tid >> 6;
  const int wm = w >> 1, wn = w & 1;
  const int g = lane >> 4, lr = lane & 15;
  const int mbase = blockIdx.y * 128, nbase = blockIdx.x * 128;

  f32x4 acc[4][4] = {};

  const int nkt = K >> 6;
  for (int kt = 0; kt < nkt; ++kt) {
    const bf16* Ag = A + (size_t)mbase * K + kt * 64;
    const bf16* Bg = Bt + (size_t)nbase * K + kt * 64;
    #pragma unroll
    for (int it = 0; it < 4; ++it) {
      int cl = it * 256 + tid;
      int row = cl >> 3, cs = cl & 7;
      int cg = cs ^ (row & 7);
      int ldsoff = (it * 256 + (tid & ~63)) * 16;
      gload16(Ag + (size_t)row * K + cg * 8, As + ldsoff);
      gload16(Bg + (size_t)row * K + cg * 8, Bs + ldsoff);
    }
    __syncthreads();
    #pragma unroll
    for (int ks = 0; ks < 2; ++ks) {
      bf16x8 af[4], bfm[4];
      #pragma unroll
      for (int mf = 0; mf < 4; ++mf) {
        int row = wm * 64 + mf * 16 + lr;
        af[mf] = *(const bf16x8*)(As + row * 128 + (((ks * 4 + g) ^ (row & 7)) << 4));
      }
      #pragma unroll
      for (int nf = 0; nf < 4; ++nf) {
        int row = wn * 64 + nf * 16 + lr;
        bfm[nf] = *(const bf16x8*)(Bs + row * 128 + (((ks * 4 + g) ^ (row & 7)) << 4));
      }
      #pragma unroll
      for (int mf = 0; mf < 4; ++mf)
        #pragma unroll
        for (int nf = 0; nf < 4; ++nf)
          acc[mf][nf] = mfma16(af[mf], bfm[nf], acc[mf][nf]);
    }
    __syncthreads();
  }

  #pragma unroll
  for (int mf = 0; mf < 4; ++mf) {
    #pragma unroll
    for (int nf = 0; nf < 4; ++nf) {
      int n = nbase + wn * 64 + nf * 16 + lr;
      float bv = bias[n];
      #pragma unroll
      for (int r = 0; r < 4; ++r) {
        int m = mbase + wm * 64 + mf * 16 + g * 4 + r;
        float val = acc[mf][nf][r] + bv;
        if constexpr (OUT_MODE == 0) {
          int b = m >> 11, s = m & 2047, h = n >> 7, d = n & 127;
          ((bf16*)Cout)[((size_t)(b * Hn + h) * Sn + s) * Dn + d] = (bf16)val;
        } else {
          ((float*)Cout)[(size_t)m * N + n] = val;
        }
      }
    }
  }
}

// ---------------- Flash attention ----------------
// 128 q-rows/block, 4 waves x 32 rows, KVBLK=64, swapped QK^T.
// Double-buffered K (global_load_lds) + V (reg-staged, kv-pair-permuted),
// raw-barrier pipeline, defer-max softmax in exp2 domain.
__global__ __launch_bounds__(256, 2) void attn(
    const bf16* __restrict__ Q, const bf16* __restrict__ K,
    const bf16* __restrict__ Vt, bf16* __restrict__ O)
{
  __shared__ __align__(16) uint8_t smem[65536];
  const int tid = threadIdx.x, lane = tid & 63, w = tid >> 6;
  const int g = lane >> 4, lr = lane & 15;
  // XCD-chunked remap: each XCD owns 8 whole heads (16 q-blocks each)
  const int lid = blockIdx.x + (int)gridDim.x * blockIdx.y;
  const int xcd = lid & 7, j = lid >> 3;
  const int bh = xcd * 8 + (j >> 4);
  const int q0 = (j & 15) * 128;
  const size_t hoff = (size_t)bh * Sn * Dn;
  const bf16* Qh = Q + hoff;
  const bf16* Kh = K + hoff;
  const bf16* Vh = Vt + hoff;   // [D][S]
  const float SC2 = 0.12751744f; // 1/sqrt(128) * log2(e)

  // ---- stage Q tile [128][256B] into smem (chunk-XOR swizzled) ----
  #pragma unroll
  for (int it = 0; it < 8; ++it) {
    int cl = it * 256 + tid;
    int row = cl >> 4, cs = cl & 15;
    int cg = cs ^ (row & 7);
    gload16(Qh + (size_t)(q0 + row) * Dn + cg * 8, smem + (it * 256 + (tid & ~63)) * 16);
  }
  __syncthreads();
  bf16x8 qf[2][4];
  #pragma unroll
  for (int nf = 0; nf < 2; ++nf)
    #pragma unroll
    for (int ks = 0; ks < 4; ++ks) {
      int row = w * 32 + nf * 16 + lr;
      qf[nf][ks] = *(const bf16x8*)(smem + row * 256 + (((ks * 4 + g) ^ (row & 7)) << 4));
    }
  __syncthreads();

  const int vd = tid >> 1, vhw = tid & 1;
  const bf16* vrow = Vh + (size_t)vd * Sn + vhw * 32;

  // prologue prefetch (tile 0): K -> LDS buf0, V -> regs
  uint4 vr0, vr1, vr2, vr3;
  #pragma unroll
  for (int it = 0; it < 4; ++it) {
    int cl = it * 256 + tid;
    int row = cl >> 4, cs = cl & 15;
    int cg = cs ^ (row & 7);
    gload16(Kh + (size_t)row * Dn + cg * 8, smem + (it * 256 + (tid & ~63)) * 16);
  }
  { const uint4* vs = (const uint4*)vrow;
    vr0 = vs[0]; vr1 = vs[1]; vr2 = vs[2]; vr3 = vs[3]; }

  f32x4 o[2][8] = {};
  float m2[2] = { -__builtin_inff(), -__builtin_inff() };
  float lrun[2] = { 0.f, 0.f };

  for (int t = 0; t < 32; ++t) {
    const int cur = t & 1;
    uint8_t* Kcur = smem + (cur << 14);            // [64][256B]
    uint8_t* Knxt = smem + ((cur ^ 1) << 14);
    uint8_t* Vcur = smem + 32768 + (cur << 14);    // [128][128B] permuted chunks
    // wait: K(t) landed in LDS, V(t) regs arrived (issued one full iter ago)
    asm volatile("s_waitcnt vmcnt(0)" ::: "memory");
    // write V(t) into Vcur, kv-pair-permuted chunks + XOR swizzle
    {
      uint8_t* base = Vcur + vd * 128;
      const int sw = vd & 7, cb = vhw * 4;
      *(uint4*)(base + (((cb + 0) ^ sw) << 4)) = make_uint4(vr0.x, vr0.y, vr2.x, vr2.y);
      *(uint4*)(base + (((cb + 1) ^ sw) << 4)) = make_uint4(vr0.z, vr0.w, vr2.z, vr2.w);
      *(uint4*)(base + (((cb + 2) ^ sw) << 4)) = make_uint4(vr1.x, vr1.y, vr3.x, vr3.y);
      *(uint4*)(base + (((cb + 3) ^ sw) << 4)) = make_uint4(vr1.z, vr1.w, vr3.z, vr3.w);
    }
    // issue prefetch for t+1 (stays in flight across both barriers)
    if (t < 31) {
      const int kvn = (t + 1) * 64;
      #pragma unroll
      for (int it = 0; it < 4; ++it) {
        int cl = it * 256 + tid;
        int row = cl >> 4, cs = cl & 15;
        int cg = cs ^ (row & 7);
        gload16(Kh + (size_t)(kvn + row) * Dn + cg * 8,
                Knxt + (it * 256 + (tid & ~63)) * 16);
      }
      const uint4* vs = (const uint4*)(vrow + kvn);
      vr0 = vs[0]; vr1 = vs[1]; vr2 = vs[2]; vr3 = vs[3];
    }
    asm volatile("s_waitcnt lgkmcnt(0)" ::: "memory");
    asm volatile("s_barrier" ::: "memory");

    // ---- QK^T (swapped): sfr[nf][mf] reg r, lane(g,lr): S^T[kv=16mf+4g+r][q=nf*16+lr]
    f32x4 sfr[2][4] = {};
    __builtin_amdgcn_s_setprio(1);
    #pragma unroll
    for (int ks = 0; ks < 4; ++ks) {
      #pragma unroll
      for (int mf = 0; mf < 4; ++mf) {
        int row = mf * 16 + lr;
        bf16x8 kf = *(const bf16x8*)(Kcur + row * 256 + (((ks * 4 + g) ^ (row & 7)) << 4));
        sfr[0][mf] = mfma16(kf, qf[0][ks], sfr[0][mf]);
        sfr[1][mf] = mfma16(kf, qf[1][ks], sfr[1][mf]);
      }
    }
    __builtin_amdgcn_s_setprio(0);

    // ---- softmax (exp2 domain, defer-max THR=8) ----
    bf16x8 pa[2][2];
    #pragma unroll
    for (int nf = 0; nf < 2; ++nf) {
      f32x4 a0, a1;
      #pragma unroll
      for (int r = 0; r < 4; ++r) a0[r] = fmaxf(sfr[nf][0][r], sfr[nf][1][r]);
      #pragma unroll
      for (int r = 0; r < 4; ++r) a1[r] = fmaxf(sfr[nf][2][r], sfr[nf][3][r]);
      #pragma unroll
      for (int r = 0; r < 4; ++r) a0[r] = fmaxf(a0[r], a1[r]);
      float mx = fmaxf(fmaxf(a0[0], a0[1]), fmaxf(a0[2], a0[3]));
      mx = fmaxf(mx, __shfl_xor(mx, 16));
      mx = fmaxf(mx, __shfl_xor(mx, 32));
      float pm2 = mx * SC2;
      if (__any(pm2 > m2[nf] + 8.f)) {
        float mnew = fmaxf(m2[nf], pm2);
        float fsc = EXP2F(m2[nf] - mnew);
        m2[nf] = mnew;
        lrun[nf] *= fsc;
        float fv[4];
        #pragma unroll
        for (int r = 0; r < 4; ++r) fv[r] = __shfl(fsc, g * 4 + r);
        #pragma unroll
        for (int df = 0; df < 8; ++df)
          #pragma unroll
          for (int r = 0; r < 4; ++r) o[nf][df][r] *= fv[r];
      }
      const float mc = m2[nf];
      f32x4 p[4];
      #pragma unroll
      for (int mf = 0; mf < 4; ++mf)
        #pragma unroll
        for (int r = 0; r < 4; ++r)
          p[mf][r] = EXP2F(__builtin_fmaf(sfr[nf][mf][r], SC2, -mc));
      f32x4 s0, s1;
      #pragma unroll
      for (int r = 0; r < 4; ++r) s0[r] = p[0][r] + p[1][r];
      #pragma unroll
      for (int r = 0; r < 4; ++r) s1[r] = p[2][r] + p[3][r];
      #pragma unroll
      for (int r = 0; r < 4; ++r) s0[r] += s1[r];
      float ps = (s0[0] + s0[1]) + (s0[2] + s0[3]);
      ps += __shfl_xor(ps, 16);
      ps += __shfl_xor(ps, 32);
      lrun[nf] += ps;
      #pragma unroll
      for (int ks = 0; ks < 2; ++ks) {
        bf16x8 tt;
        #pragma unroll
        for (int i = 0; i < 4; ++i) {
          tt[i]     = (bf16)p[2 * ks][i];
          tt[i + 4] = (bf16)p[2 * ks + 1][i];
        }
        pa[nf][ks] = tt;
      }
    }

    // ---- PV: o[q][d] += P @ V ----
    __builtin_amdgcn_s_setprio(1);
    #pragma unroll
    for (int ks = 0; ks < 2; ++ks) {
      #pragma unroll
      for (int df = 0; df < 8; ++df) {
        int row = df * 16 + lr;
        bf16x8 vf = *(const bf16x8*)(Vcur + row * 128 + (((ks * 4 + g) ^ (row & 7)) << 4));
        o[0][df] = mfma16(pa[0][ks], vf, o[0][df]);
        o[1][df] = mfma16(pa[1][ks], vf, o[1][df]);
      }
    }
    __builtin_amdgcn_s_setprio(0);
    asm volatile("s_barrier" ::: "memory");
  }

  // ---- finalize ----
  const int b = bh >> 4, h = bh & 15;
  #pragma unroll
  for (int nf = 0; nf < 2; ++nf) {
    float inv = 1.f / lrun[nf];
    float iv[4];
    #pragma unroll
    for (int r = 0; r < 4; ++r) iv[r] = __shfl(inv, g * 4 + r);
    #pragma unroll
    for (int df = 0; df < 8; ++df) {
      #pragma unroll
      for (int r = 0; r < 4; ++r) {
        int qrow = q0 + w * 32 + nf * 16 + g * 4 + r;
        int d = df * 16 + lr;
        size_t m = (size_t)b * Sn + qrow;
        O[m * En + h * Dn + d] = (bf16)(o[nf][df][r] * iv[r]);
      }
    }
  }
}

// ---------------- host ----------------
extern "C" void kernel_launch(void* const* d_in, const int* in_sizes, int n_in,
                              void* d_out, int out_size, void* d_ws, size_t ws_size,
                              hipStream_t stream) {
  const float* X  = (const float*)d_in[0];
  const float* Wq = (const float*)d_in[1];
  const float* bq = (const float*)d_in[2];
  const float* Wk = (const float*)d_in[3];
  const float* bk = (const float*)d_in[4];
  const float* Wv = (const float*)d_in[5];
  const float* bv = (const float*)d_in[6];
  const float* Wo = (const float*)d_in[7];
  const float* bo = (const float*)d_in[8];

  bf16* ws = (bf16*)d_ws;
  const size_t szE = (size_t)Mn * En;
  const size_t szW = (size_t)En * En;
  bf16* Xb  = ws;
  bf16* Wqt = Xb + szE;
  bf16* Wkt = Wqt + szW;
  bf16* Wvt = Wkt + szW;
  bf16* Wot = Wvt + szW;
  bf16* Qb  = Wot + szW;
  bf16* Kb  = Qb + szE;
  bf16* Vb  = Kb + szE;
  bf16* Vtp = Vb + szE;
  bf16* AO  = Vb;   // alias: V consumed by vtrans before attn writes AO

  cvt_x<<<2048, 256, 0, stream>>>(X, Xb, (int)(szE / 8));
  wtrans<<<dim3(32, 32), 256, 0, stream>>>(Wq, Wqt);
  wtrans<<<dim3(32, 32), 256, 0, stream>>>(Wk, Wkt);
  wtrans<<<dim3(32, 32), 256, 0, stream>>>(Wv, Wvt);
  wtrans<<<dim3(32, 32), 256, 0, stream>>>(Wo, Wot);
  gemm_bt<0><<<dim3(16, 64), 256, 0, stream>>>(Xb, Wqt, bq, Qb, Mn, En, En);
  gemm_bt<0><<<dim3(16, 64), 256, 0, stream>>>(Xb, Wkt, bk, Kb, Mn, En, En);
  gemm_bt<0><<<dim3(16, 64), 256, 0, stream>>>(Xb, Wvt, bv, Vb, Mn, En, En);
  vtrans<<<dim3(32, 2, 64), 256, 0, stream>>>(Vb, Vtp);
  attn<<<dim3(16, 64), 256, 0, stream>>>(Qb, Kb, Vtp, AO);
  gemm_bt<1><<<dim3(16, 64), 256, 0, stream>>>(AO, Wot, bo, d_out, Mn, En, En);
}

// Round 4
// 505.913 us; speedup vs baseline: 1.3398x; 1.0067x over previous
//
#include <hip/hip_runtime.h>
#include <hip/hip_bf16.h>
#include <stdint.h>

typedef __bf16 bf16;
typedef float f32x4 __attribute__((ext_vector_type(4)));
typedef bf16 bf16x4 __attribute__((ext_vector_type(4)));
typedef bf16 bf16x8 __attribute__((ext_vector_type(8)));

#define DEV __device__ __forceinline__

DEV void gload16(const void* g, void* l) {
  __builtin_amdgcn_global_load_lds((const __attribute__((address_space(1))) void*)g,
                                   (__attribute__((address_space(3))) void*)l, 16, 0, 0);
}

DEV f32x4 mfma16(bf16x8 a, bf16x8 b, f32x4 c) {
  return __builtin_amdgcn_mfma_f32_16x16x32_bf16(a, b, c, 0, 0, 0);
}

#if __has_builtin(__builtin_amdgcn_exp2f)
DEV float EXP2F(float x) { return __builtin_amdgcn_exp2f(x); }
#else
DEV float EXP2F(float x) { return exp2f(x); }
#endif

static constexpr int Bn = 4, Sn = 2048, Hn = 16, Dn = 128, En = 2048, Mn = 8192;

// ---------------- fp32 -> bf16 elementwise (X) ----------------
__global__ void cvt_x(const float* __restrict__ in, bf16* __restrict__ out, int n8) {
  int i = blockIdx.x * blockDim.x + threadIdx.x;
  int stride = gridDim.x * blockDim.x;
  for (int idx = i; idx < n8; idx += stride) {
    const float4* p = (const float4*)(in + (size_t)idx * 8);
    float4 a = p[0], b = p[1];
    bf16x8 o;
    o[0]=(bf16)a.x; o[1]=(bf16)a.y; o[2]=(bf16)a.z; o[3]=(bf16)a.w;
    o[4]=(bf16)b.x; o[5]=(bf16)b.y; o[6]=(bf16)b.z; o[7]=(bf16)b.w;
    *(bf16x8*)(out + (size_t)idx * 8) = o;
  }
}

// ---------------- W [K][N] fp32 -> Wt [N][K] bf16 (2048x2048) ----------------
__global__ void wtrans(const float* __restrict__ W, bf16* __restrict__ Wt) {
  __shared__ bf16 t[64][65];
  int tx = threadIdx.x & 15, ty = threadIdx.x >> 4;
  int c0 = blockIdx.x * 64, r0 = blockIdx.y * 64;
  #pragma unroll
  for (int i = 0; i < 4; ++i) {
    int r = i * 16 + ty;
    float4 v = *(const float4*)&W[(size_t)(r0 + r) * En + c0 + tx * 4];
    t[r][tx*4+0] = (bf16)v.x; t[r][tx*4+1] = (bf16)v.y;
    t[r][tx*4+2] = (bf16)v.z; t[r][tx*4+3] = (bf16)v.w;
  }
  __syncthreads();
  #pragma unroll
  for (int i = 0; i < 4; ++i) {
    int c = i * 16 + ty;
    bf16x4 o;
    #pragma unroll
    for (int j = 0; j < 4; ++j) o[j] = t[tx*4+j][c];
    *(bf16x4*)&Wt[(size_t)(c0 + c) * En + r0 + tx * 4] = o;
  }
}

// ---------------- V [bh][S][D] bf16 -> Vt [bh][D][S] bf16 ----------------
__global__ void vtrans(const bf16* __restrict__ V, bf16* __restrict__ Vt) {
  __shared__ bf16 t[64][65];
  int tx = threadIdx.x & 15, ty = threadIdx.x >> 4;
  int s0 = blockIdx.x * 64, d0 = blockIdx.y * 64, bh = blockIdx.z;
  const bf16* Vi = V + (size_t)bh * Sn * Dn;
  bf16* Vo = Vt + (size_t)bh * Sn * Dn;
  #pragma unroll
  for (int i = 0; i < 4; ++i) {
    int r = i * 16 + ty;
    bf16x4 v = *(const bf16x4*)&Vi[(size_t)(s0 + r) * Dn + d0 + tx * 4];
    #pragma unroll
    for (int j = 0; j < 4; ++j) t[r][tx*4+j] = v[j];
  }
  __syncthreads();
  #pragma unroll
  for (int i = 0; i < 4; ++i) {
    int dd = i * 16 + ty;
    bf16x4 o;
    #pragma unroll
    for (int j = 0; j < 4; ++j) o[j] = t[tx*4+j][dd];
    *(bf16x4*)&Vo[(size_t)(d0 + dd) * Sn + s0 + tx * 4] = o;
  }
}

// ---------------- 256x256 8-phase GEMM: C = A[M][K] @ Bt[N][K]^T + bias ----
// 8 waves (2M x 4N), BK=64, K-half-major LDS [buf][kh][256][64B], 128KiB.
// Counted vmcnt(4) gating (never 0 in main loop), raw barriers, setprio MFMA.
// OUT_MODE 0: QKV fused -> bf16 [tsel][B][H][S][D]; OUT_MODE 1: fp32 [M][N].
#define STAGE_A(H, DBUF, KTN) do { \
    const bf16* s_ = A + (size_t)(mbase + (tid >> 2)) * K + (KTN) * 64 + (H) * 32 + (tid & 3) * 8; \
    uint8_t* d_ = (DBUF) + (H) * 16384 + (w << 10); \
    gload16(s_, d_); \
    gload16(s_ + (size_t)128 * K, d_ + 8192); \
  } while (0)
#define STAGE_B(H, DBUF, KTN) do { \
    const bf16* s_ = Bt + (size_t)(nbase + (tid >> 2)) * K + (KTN) * 64 + (H) * 32 + (tid & 3) * 8; \
    uint8_t* d_ = (DBUF) + (H) * 16384 + (w << 10); \
    gload16(s_, d_); \
    gload16(s_ + (size_t)128 * K, d_ + 8192); \
  } while (0)

template<int OUT_MODE>
__global__ __launch_bounds__(512, 2) void gemm256(
    const bf16* __restrict__ A, const bf16* __restrict__ Bt,
    const float* __restrict__ b0, const float* __restrict__ b1,
    const float* __restrict__ b2, void* __restrict__ Cout,
    int M, int N, int K, int nbx)
{
  __shared__ __align__(16) uint8_t smem[131072];
  const int tid = threadIdx.x, lane = tid & 63, w = tid >> 6;
  const int wm = w >> 2, wn = w & 3;
  const int g = lane >> 4, lr = lane & 15;
  // bijective XCD-chunked swizzle (gridDim.x % 8 == 0)
  const int lid = blockIdx.x;
  const int swz = (lid & 7) * ((int)gridDim.x >> 3) + (lid >> 3);
  const int bx = swz % nbx, by = swz / nbx;
  const int mbase = by * 256, nbase = bx * 256;

  f32x4 acc[8][4] = {};

  // prologue: stage tile 0 into buf0 (Ah0, Bh0, Ah1, Bh1), one-time drain
  STAGE_A(0, smem, 0);
  STAGE_B(0, smem + 65536, 0);
  STAGE_A(1, smem, 0);
  STAGE_B(1, smem + 65536, 0);
  asm volatile("s_waitcnt vmcnt(0)" ::: "memory");
  __builtin_amdgcn_s_barrier();

  const int NKT = K >> 6;
  for (int kt = 0; kt < NKT; ++kt) {
    const int cur = kt & 1;
    uint8_t* Acur = smem + (cur << 15);
    uint8_t* Bcur = smem + 65536 + (cur << 15);
    uint8_t* Anxt = smem + ((cur ^ 1) << 15);
    uint8_t* Bnxt = smem + 65536 + ((cur ^ 1) << 15);
    const bool notlast = (kt + 1 < NKT);
    bf16x8 af[8], bfr0, bfr1;

    // ---- phase 0: ks=0, qn=0; stage Ah0(t+1)
    asm volatile("s_waitcnt vmcnt(4)" ::: "memory");
    #pragma unroll
    for (int mf = 0; mf < 8; ++mf)
      af[mf] = *(const bf16x8*)(Acur + (wm * 128 + mf * 16 + lr) * 64 + g * 16);
    bfr0 = *(const bf16x8*)(Bcur + (wn * 64 +  0 + lr) * 64 + g * 16);
    bfr1 = *(const bf16x8*)(Bcur + (wn * 64 + 16 + lr) * 64 + g * 16);
    if (notlast) STAGE_A(0, Anxt, kt + 1);
    __builtin_amdgcn_s_barrier();
    asm volatile("s_waitcnt lgkmcnt(0)" ::: "memory");
    __builtin_amdgcn_sched_barrier(0);
    __builtin_amdgcn_s_setprio(1);
    #pragma unroll
    for (int mf = 0; mf < 8; ++mf) {
      acc[mf][0] = mfma16(af[mf], bfr0, acc[mf][0]);
      acc[mf][1] = mfma16(af[mf], bfr1, acc[mf][1]);
    }
    __builtin_amdgcn_s_setprio(0);
    __builtin_amdgcn_s_barrier();

    // ---- phase 1: ks=0, qn=1 (reuse af); stage Bh0(t+1)
    bfr0 = *(const bf16x8*)(Bcur + (wn * 64 + 32 + lr) * 64 + g * 16);
    bfr1 = *(const bf16x8*)(Bcur + (wn * 64 + 48 + lr) * 64 + g * 16);
    if (notlast) STAGE_B(0, Bnxt, kt + 1);
    __builtin_amdgcn_s_barrier();
    asm volatile("s_waitcnt lgkmcnt(0)" ::: "memory");
    __builtin_amdgcn_sched_barrier(0);
    __builtin_amdgcn_s_setprio(1);
    #pragma unroll
    for (int mf = 0; mf < 8; ++mf) {
      acc[mf][2] = mfma16(af[mf], bfr0, acc[mf][2]);
      acc[mf][3] = mfma16(af[mf], bfr1, acc[mf][3]);
    }
    __builtin_amdgcn_s_setprio(0);
    __builtin_amdgcn_s_barrier();

    // ---- phase 2: ks=1, qn=0; stage Ah1(t+1)
    if (notlast) { asm volatile("s_waitcnt vmcnt(4)" ::: "memory"); }
    else         { asm volatile("s_waitcnt vmcnt(0)" ::: "memory"); }
    #pragma unroll
    for (int mf = 0; mf < 8; ++mf)
      af[mf] = *(const bf16x8*)(Acur + 16384 + (wm * 128 + mf * 16 + lr) * 64 + g * 16);
    bfr0 = *(const bf16x8*)(Bcur + 16384 + (wn * 64 +  0 + lr) * 64 + g * 16);
    bfr1 = *(const bf16x8*)(Bcur + 16384 + (wn * 64 + 16 + lr) * 64 + g * 16);
    if (notlast) STAGE_A(1, Anxt, kt + 1);
    __builtin_amdgcn_s_barrier();
    asm volatile("s_waitcnt lgkmcnt(0)" ::: "memory");
    __builtin_amdgcn_sched_barrier(0);
    __builtin_amdgcn_s_setprio(1);
    #pragma unroll
    for (int mf = 0; mf < 8; ++mf) {
      acc[mf][0] = mfma16(af[mf], bfr0, acc[mf][0]);
      acc[mf][1] = mfma16(af[mf], bfr1, acc[mf][1]);
    }
    __builtin_amdgcn_s_setprio(0);
    __builtin_amdgcn_s_barrier();

    // ---- phase 3: ks=1, qn=1 (reuse af); stage Bh1(t+1)
    bfr0 = *(const bf16x8*)(Bcur + 16384 + (wn * 64 + 32 + lr) * 64 + g * 16);
    bfr1 = *(const bf16x8*)(Bcur + 16384 + (wn * 64 + 48 + lr) * 64 + g * 16);
    if (notlast) STAGE_B(1, Bnxt, kt + 1);
    __builtin_amdgcn_s_barrier();
    asm volatile("s_waitcnt lgkmcnt(0)" ::: "memory");
    __builtin_amdgcn_sched_barrier(0);
    __builtin_amdgcn_s_setprio(1);
    #pragma unroll
    for (int mf = 0; mf < 8; ++mf) {
      acc[mf][2] = mfma16(af[mf], bfr0, acc[mf][2]);
      acc[mf][3] = mfma16(af[mf], bfr1, acc[mf][3]);
    }
    __builtin_amdgcn_s_setprio(0);
    __builtin_amdgcn_s_barrier();
  }

  // ---- epilogue ----
  int tsel = 0;
  const float* bsel = b0;
  if constexpr (OUT_MODE == 0) {
    tsel = nbase >> 11;
    bsel = (tsel == 0) ? b0 : ((tsel == 1) ? b1 : b2);
  }
  #pragma unroll
  for (int j = 0; j < 4; ++j) {
    int n = nbase + wn * 64 + j * 16 + lr;
    float bv = (OUT_MODE == 0) ? bsel[n & 2047] : bsel[n];
    #pragma unroll
    for (int mf = 0; mf < 8; ++mf) {
      #pragma unroll
      for (int r = 0; r < 4; ++r) {
        int m = mbase + wm * 128 + mf * 16 + g * 4 + r;
        float val = acc[mf][j][r] + bv;
        if constexpr (OUT_MODE == 0) {
          int b = m >> 11, s = m & 2047, nn = n & 2047, h = nn >> 7, d = nn & 127;
          ((bf16*)Cout)[(size_t)tsel * ((size_t)Mn * En) +
                        ((size_t)(b * Hn + h) * Sn + s) * Dn + d] = (bf16)val;
        } else {
          ((float*)Cout)[(size_t)m * N + n] = val;
        }
      }
    }
  }
}

// ---------------- Flash attention (unchanged from round 3) ----------------
__global__ __launch_bounds__(256, 2) void attn(
    const bf16* __restrict__ Q, const bf16* __restrict__ K,
    const bf16* __restrict__ Vt, bf16* __restrict__ O)
{
  __shared__ __align__(16) uint8_t smem[65536];
  const int tid = threadIdx.x, lane = tid & 63, w = tid >> 6;
  const int g = lane >> 4, lr = lane & 15;
  const int lid = blockIdx.x + (int)gridDim.x * blockIdx.y;
  const int xcd = lid & 7, j = lid >> 3;
  const int bh = xcd * 8 + (j >> 4);
  const int q0 = (j & 15) * 128;
  const size_t hoff = (size_t)bh * Sn * Dn;
  const bf16* Qh = Q + hoff;
  const bf16* Kh = K + hoff;
  const bf16* Vh = Vt + hoff;   // [D][S]
  const float SC2 = 0.12751744f; // 1/sqrt(128) * log2(e)

  #pragma unroll
  for (int it = 0; it < 8; ++it) {
    int cl = it * 256 + tid;
    int row = cl >> 4, cs = cl & 15;
    int cg = cs ^ (row & 7);
    gload16(Qh + (size_t)(q0 + row) * Dn + cg * 8, smem + (it * 256 + (tid & ~63)) * 16);
  }
  __syncthreads();
  bf16x8 qf[2][4];
  #pragma unroll
  for (int nf = 0; nf < 2; ++nf)
    #pragma unroll
    for (int ks = 0; ks < 4; ++ks) {
      int row = w * 32 + nf * 16 + lr;
      qf[nf][ks] = *(const bf16x8*)(smem + row * 256 + (((ks * 4 + g) ^ (row & 7)) << 4));
    }
  __syncthreads();

  const int vd = tid >> 1, vhw = tid & 1;
  const bf16* vrow = Vh + (size_t)vd * Sn + vhw * 32;

  uint4 vr0, vr1, vr2, vr3;
  #pragma unroll
  for (int it = 0; it < 4; ++it) {
    int cl = it * 256 + tid;
    int row = cl >> 4, cs = cl & 15;
    int cg = cs ^ (row & 7);
    gload16(Kh + (size_t)row * Dn + cg * 8, smem + (it * 256 + (tid & ~63)) * 16);
  }
  { const uint4* vs = (const uint4*)vrow;
    vr0 = vs[0]; vr1 = vs[1]; vr2 = vs[2]; vr3 = vs[3]; }

  f32x4 o[2][8] = {};
  float m2[2] = { -__builtin_inff(), -__builtin_inff() };
  float lrun[2] = { 0.f, 0.f };

  for (int t = 0; t < 32; ++t) {
    const int cur = t & 1;
    uint8_t* Kcur = smem + (cur << 14);
    uint8_t* Knxt = smem + ((cur ^ 1) << 14);
    uint8_t* Vcur = smem + 32768 + (cur << 14);
    asm volatile("s_waitcnt vmcnt(0)" ::: "memory");
    {
      uint8_t* base = Vcur + vd * 128;
      const int sw = vd & 7, cb = vhw * 4;
      *(uint4*)(base + (((cb + 0) ^ sw) << 4)) = make_uint4(vr0.x, vr0.y, vr2.x, vr2.y);
      *(uint4*)(base + (((cb + 1) ^ sw) << 4)) = make_uint4(vr0.z, vr0.w, vr2.z, vr2.w);
      *(uint4*)(base + (((cb + 2) ^ sw) << 4)) = make_uint4(vr1.x, vr1.y, vr3.x, vr3.y);
      *(uint4*)(base + (((cb + 3) ^ sw) << 4)) = make_uint4(vr1.z, vr1.w, vr3.z, vr3.w);
    }
    if (t < 31) {
      const int kvn = (t + 1) * 64;
      #pragma unroll
      for (int it = 0; it < 4; ++it) {
        int cl = it * 256 + tid;
        int row = cl >> 4, cs = cl & 15;
        int cg = cs ^ (row & 7);
        gload16(Kh + (size_t)(kvn + row) * Dn + cg * 8,
                Knxt + (it * 256 + (tid & ~63)) * 16);
      }
      const uint4* vs = (const uint4*)(vrow + kvn);
      vr0 = vs[0]; vr1 = vs[1]; vr2 = vs[2]; vr3 = vs[3];
    }
    asm volatile("s_waitcnt lgkmcnt(0)" ::: "memory");
    asm volatile("s_barrier" ::: "memory");

    f32x4 sfr[2][4] = {};
    __builtin_amdgcn_s_setprio(1);
    #pragma unroll
    for (int ks = 0; ks < 4; ++ks) {
      #pragma unroll
      for (int mf = 0; mf < 4; ++mf) {
        int row = mf * 16 + lr;
        bf16x8 kf = *(const bf16x8*)(Kcur + row * 256 + (((ks * 4 + g) ^ (row & 7)) << 4));
        sfr[0][mf] = mfma16(kf, qf[0][ks], sfr[0][mf]);
        sfr[1][mf] = mfma16(kf, qf[1][ks], sfr[1][mf]);
      }
    }
    __builtin_amdgcn_s_setprio(0);

    bf16x8 pa[2][2];
    #pragma unroll
    for (int nf = 0; nf < 2; ++nf) {
      f32x4 a0, a1;
      #pragma unroll
      for (int r = 0; r < 4; ++r) a0[r] = fmaxf(sfr[nf][0][r], sfr[nf][1][r]);
      #pragma unroll
      for (int r = 0; r < 4; ++r) a1[r] = fmaxf(sfr[nf][2][r], sfr[nf][3][r]);
      #pragma unroll
      for (int r = 0; r < 4; ++r) a0[r] = fmaxf(a0[r], a1[r]);
      float mx = fmaxf(fmaxf(a0[0], a0[1]), fmaxf(a0[2], a0[3]));
      mx = fmaxf(mx, __shfl_xor(mx, 16));
      mx = fmaxf(mx, __shfl_xor(mx, 32));
      float pm2 = mx * SC2;
      if (__any(pm2 > m2[nf] + 8.f)) {
        float mnew = fmaxf(m2[nf], pm2);
        float fsc = EXP2F(m2[nf] - mnew);
        m2[nf] = mnew;
        lrun[nf] *= fsc;
        float fv[4];
        #pragma unroll
        for (int r = 0; r < 4; ++r) fv[r] = __shfl(fsc, g * 4 + r);
        #pragma unroll
        for (int df = 0; df < 8; ++df)
          #pragma unroll
          for (int r = 0; r < 4; ++r) o[nf][df][r] *= fv[r];
      }
      const float mc = m2[nf];
      f32x4 p[4];
      #pragma unroll
      for (int mf = 0; mf < 4; ++mf)
        #pragma unroll
        for (int r = 0; r < 4; ++r)
          p[mf][r] = EXP2F(__builtin_fmaf(sfr[nf][mf][r], SC2, -mc));
      f32x4 s0, s1;
      #pragma unroll
      for (int r = 0; r < 4; ++r) s0[r] = p[0][r] + p[1][r];
      #pragma unroll
      for (int r = 0; r < 4; ++r) s1[r] = p[2][r] + p[3][r];
      #pragma unroll
      for (int r = 0; r < 4; ++r) s0[r] += s1[r];
      float ps = (s0[0] + s0[1]) + (s0[2] + s0[3]);
      ps += __shfl_xor(ps, 16);
      ps += __shfl_xor(ps, 32);
      lrun[nf] += ps;
      #pragma unroll
      for (int ks = 0; ks < 2; ++ks) {
        bf16x8 tt;
        #pragma unroll
        for (int i = 0; i < 4; ++i) {
          tt[i]     = (bf16)p[2 * ks][i];
          tt[i + 4] = (bf16)p[2 * ks + 1][i];
        }
        pa[nf][ks] = tt;
      }
    }

    __builtin_amdgcn_s_setprio(1);
    #pragma unroll
    for (int ks = 0; ks < 2; ++ks) {
      #pragma unroll
      for (int df = 0; df < 8; ++df) {
        int row = df * 16 + lr;
        bf16x8 vf = *(const bf16x8*)(Vcur + row * 128 + (((ks * 4 + g) ^ (row & 7)) << 4));
        o[0][df] = mfma16(pa[0][ks], vf, o[0][df]);
        o[1][df] = mfma16(pa[1][ks], vf, o[1][df]);
      }
    }
    __builtin_amdgcn_s_setprio(0);
    asm volatile("s_barrier" ::: "memory");
  }

  const int b = bh >> 4, h = bh & 15;
  #pragma unroll
  for (int nf = 0; nf < 2; ++nf) {
    float inv = 1.f / lrun[nf];
    float iv[4];
    #pragma unroll
    for (int r = 0; r < 4; ++r) iv[r] = __shfl(inv, g * 4 + r);
    #pragma unroll
    for (int df = 0; df < 8; ++df) {
      #pragma unroll
      for (int r = 0; r < 4; ++r) {
        int qrow = q0 + w * 32 + nf * 16 + g * 4 + r;
        int d = df * 16 + lr;
        size_t m = (size_t)b * Sn + qrow;
        O[m * En + h * Dn + d] = (bf16)(o[nf][df][r] * iv[r]);
      }
    }
  }
}

// ---------------- host ----------------
extern "C" void kernel_launch(void* const* d_in, const int* in_sizes, int n_in,
                              void* d_out, int out_size, void* d_ws, size_t ws_size,
                              hipStream_t stream) {
  const float* X  = (const float*)d_in[0];
  const float* Wq = (const float*)d_in[1];
  const float* bq = (const float*)d_in[2];
  const float* Wk = (const float*)d_in[3];
  const float* bk = (const float*)d_in[4];
  const float* Wv = (const float*)d_in[5];
  const float* bv = (const float*)d_in[6];
  const float* Wo = (const float*)d_in[7];
  const float* bo = (const float*)d_in[8];

  bf16* ws = (bf16*)d_ws;
  const size_t szE = (size_t)Mn * En;
  const size_t szW = (size_t)En * En;
  bf16* Xb  = ws;
  bf16* Wqt = Xb + szE;      // Wqt/Wkt/Wvt contiguous => fused QKV B-matrix [6144][2048]
  bf16* Wkt = Wqt + szW;
  bf16* Wvt = Wkt + szW;
  bf16* Wot = Wvt + szW;
  bf16* Qb  = Wot + szW;     // Q/K/V contiguous => tsel*szE addressing in epilogue
  bf16* Kb  = Qb + szE;
  bf16* Vb  = Kb + szE;
  bf16* Vtp = Vb + szE;
  bf16* AO  = Vb;            // alias: V consumed by vtrans before attn writes AO

  cvt_x<<<2048, 256, 0, stream>>>(X, Xb, (int)(szE / 8));
  wtrans<<<dim3(32, 32), 256, 0, stream>>>(Wq, Wqt);
  wtrans<<<dim3(32, 32), 256, 0, stream>>>(Wk, Wkt);
  wtrans<<<dim3(32, 32), 256, 0, stream>>>(Wv, Wvt);
  wtrans<<<dim3(32, 32), 256, 0, stream>>>(Wo, Wot);
  // fused QKV: M=8192, N=6144 (Q|K|V), K=2048 ; grid 768 (%8==0)
  gemm256<0><<<768, 512, 0, stream>>>(Xb, Wqt, bq, bk, bv, Qb, Mn, 3 * En, En, 24);
  vtrans<<<dim3(32, 2, 64), 256, 0, stream>>>(Vb, Vtp);
  attn<<<dim3(16, 64), 256, 0, stream>>>(Qb, Kb, Vtp, AO);
  // output projection: M=8192, N=2048 ; grid 256 (%8==0)
  gemm256<1><<<256, 512, 0, stream>>>(AO, Wot, bo, nullptr, nullptr, d_out, Mn, En, En, 8);
}

// Round 6
// 493.580 us; speedup vs baseline: 1.3733x; 1.0250x over previous
//
#include <hip/hip_runtime.h>
#include <hip/hip_bf16.h>
#include <stdint.h>

typedef __bf16 bf16;
typedef float f32x4 __attribute__((ext_vector_type(4)));
typedef bf16 bf16x4 __attribute__((ext_vector_type(4)));
typedef bf16 bf16x8 __attribute__((ext_vector_type(8)));

#define DEV __device__ __forceinline__

DEV void gload16(const void* g, void* l) {
  __builtin_amdgcn_global_load_lds((const __attribute__((address_space(1))) void*)g,
                                   (__attribute__((address_space(3))) void*)l, 16, 0, 0);
}

DEV f32x4 mfma16(bf16x8 a, bf16x8 b, f32x4 c) {
  return __builtin_amdgcn_mfma_f32_16x16x32_bf16(a, b, c, 0, 0, 0);
}

#if __has_builtin(__builtin_amdgcn_exp2f)
DEV float EXP2F(float x) { return __builtin_amdgcn_exp2f(x); }
#else
DEV float EXP2F(float x) { return exp2f(x); }
#endif

static constexpr int Bn = 4, Sn = 2048, Hn = 16, Dn = 128, En = 2048, Mn = 8192;

// ---------------- fp32 -> bf16 elementwise (X) ----------------
__global__ void cvt_x(const float* __restrict__ in, bf16* __restrict__ out, int n8) {
  int i = blockIdx.x * blockDim.x + threadIdx.x;
  int stride = gridDim.x * blockDim.x;
  for (int idx = i; idx < n8; idx += stride) {
    const float4* p = (const float4*)(in + (size_t)idx * 8);
    float4 a = p[0], b = p[1];
    bf16x8 o;
    o[0]=(bf16)a.x; o[1]=(bf16)a.y; o[2]=(bf16)a.z; o[3]=(bf16)a.w;
    o[4]=(bf16)b.x; o[5]=(bf16)b.y; o[6]=(bf16)b.z; o[7]=(bf16)b.w;
    *(bf16x8*)(out + (size_t)idx * 8) = o;
  }
}

// ---------------- W [K][N] fp32 -> Wt [N][K] bf16 (2048x2048) ----------------
__global__ void wtrans(const float* __restrict__ W, bf16* __restrict__ Wt) {
  __shared__ bf16 t[64][65];
  int tx = threadIdx.x & 15, ty = threadIdx.x >> 4;
  int c0 = blockIdx.x * 64, r0 = blockIdx.y * 64;
  #pragma unroll
  for (int i = 0; i < 4; ++i) {
    int r = i * 16 + ty;
    float4 v = *(const float4*)&W[(size_t)(r0 + r) * En + c0 + tx * 4];
    t[r][tx*4+0] = (bf16)v.x; t[r][tx*4+1] = (bf16)v.y;
    t[r][tx*4+2] = (bf16)v.z; t[r][tx*4+3] = (bf16)v.w;
  }
  __syncthreads();
  #pragma unroll
  for (int i = 0; i < 4; ++i) {
    int c = i * 16 + ty;
    bf16x4 o;
    #pragma unroll
    for (int j = 0; j < 4; ++j) o[j] = t[tx*4+j][c];
    *(bf16x4*)&Wt[(size_t)(c0 + c) * En + r0 + tx * 4] = o;
  }
}

// ---------------- V [bh][S][D] bf16 -> Vt [bh][D][S] bf16 ----------------
__global__ void vtrans(const bf16* __restrict__ V, bf16* __restrict__ Vt) {
  __shared__ bf16 t[64][65];
  int tx = threadIdx.x & 15, ty = threadIdx.x >> 4;
  int s0 = blockIdx.x * 64, d0 = blockIdx.y * 64, bh = blockIdx.z;
  const bf16* Vi = V + (size_t)bh * Sn * Dn;
  bf16* Vo = Vt + (size_t)bh * Sn * Dn;
  #pragma unroll
  for (int i = 0; i < 4; ++i) {
    int r = i * 16 + ty;
    bf16x4 v = *(const bf16x4*)&Vi[(size_t)(s0 + r) * Dn + d0 + tx * 4];
    #pragma unroll
    for (int j = 0; j < 4; ++j) t[r][tx*4+j] = v[j];
  }
  __syncthreads();
  #pragma unroll
  for (int i = 0; i < 4; ++i) {
    int dd = i * 16 + ty;
    bf16x4 o;
    #pragma unroll
    for (int j = 0; j < 4; ++j) o[j] = t[tx*4+j][dd];
    *(bf16x4*)&Vo[(size_t)(d0 + dd) * Sn + s0 + tx * 4] = o;
  }
}

// ---------------- 256x256 8-phase GEMM: C = A[M][K] @ Bt[N][K]^T + bias ----
// 8 waves (2M x 4N), BK=64, K-half-major LDS [buf][kh][256 rows][64B], 128KiB.
// Bank-conflict swizzle (r5): 16B chunk XOR'd with (row>>1)&3; read side uses
// (lr>>1)&3 (lane-only => identity composition, verified). Stage side: linear
// LDS dest + pre-swizzled GLOBAL source chunk.
// Race fix (r6): vmcnt gates moved to BEFORE the end-of-phase barriers of
// P1/P3. Invariant: each wave retires its own global_load_lds ops, THEN the
// barrier joins all waves, THEN any wave may ds_read the staged region.
// (vmcnt is per-wave; reads consume rows staged by other waves.)
#define STAGE_A(H, DBUF, KTN) do { \
    const bf16* s_ = A + (size_t)(mbase + (tid >> 2)) * K + (KTN) * 64 + (H) * 32 \
                     + (((tid & 3) ^ ((tid >> 3) & 3)) * 8); \
    uint8_t* d_ = (DBUF) + (H) * 16384 + (w << 10); \
    gload16(s_, d_); \
    gload16(s_ + (size_t)128 * K, d_ + 8192); \
  } while (0)
#define STAGE_B(H, DBUF, KTN) do { \
    const bf16* s_ = Bt + (size_t)(nbase + (tid >> 2)) * K + (KTN) * 64 + (H) * 32 \
                     + (((tid & 3) ^ ((tid >> 3) & 3)) * 8); \
    uint8_t* d_ = (DBUF) + (H) * 16384 + (w << 10); \
    gload16(s_, d_); \
    gload16(s_ + (size_t)128 * K, d_ + 8192); \
  } while (0)

template<int OUT_MODE>
__global__ __launch_bounds__(512, 2) void gemm256(
    const bf16* __restrict__ A, const bf16* __restrict__ Bt,
    const float* __restrict__ b0, const float* __restrict__ b1,
    const float* __restrict__ b2, void* __restrict__ Cout,
    int M, int N, int K, int nbx)
{
  __shared__ __align__(16) uint8_t smem[131072];
  const int tid = threadIdx.x, lane = tid & 63, w = tid >> 6;
  const int wm = w >> 2, wn = w & 3;
  const int g = lane >> 4, lr = lane & 15;
  const int gx = (g ^ ((lr >> 1) & 3)) << 4;   // swizzled 16B-chunk byte offset
  // bijective XCD-chunked swizzle (gridDim.x % 8 == 0)
  const int lid = blockIdx.x;
  const int swz = (lid & 7) * ((int)gridDim.x >> 3) + (lid >> 3);
  const int bx = swz % nbx, by = swz / nbx;
  const int mbase = by * 256, nbase = bx * 256;

  f32x4 acc[8][4] = {};

  // prologue: stage tile 0 into buf0 (Ah0, Bh0, Ah1, Bh1).
  // vmcnt(4) retires Ah0,Bh0 (the oldest 4 ops); Ah1,Bh1 stay in flight.
  STAGE_A(0, smem, 0);
  STAGE_B(0, smem + 65536, 0);
  STAGE_A(1, smem, 0);
  STAGE_B(1, smem + 65536, 0);
  asm volatile("s_waitcnt vmcnt(4)" ::: "memory");
  __builtin_amdgcn_s_barrier();

  const int NKT = K >> 6;
  for (int kt = 0; kt < NKT; ++kt) {
    const int cur = kt & 1;
    uint8_t* Acur = smem + (cur << 15);
    uint8_t* Bcur = smem + 65536 + (cur << 15);
    uint8_t* Anxt = smem + ((cur ^ 1) << 15);
    uint8_t* Bnxt = smem + 65536 + ((cur ^ 1) << 15);
    const bool notlast = (kt + 1 < NKT);
    bf16x8 af[8], bfr0, bfr1;

    // ---- phase 0: ks=0, qn=0; stage Ah0(t+1)
    // (Ah0,Bh0 of cur guaranteed by vmcnt before the barrier we just crossed)
    #pragma unroll
    for (int mf = 0; mf < 8; ++mf)
      af[mf] = *(const bf16x8*)(Acur + (wm * 128 + mf * 16 + lr) * 64 + gx);
    bfr0 = *(const bf16x8*)(Bcur + (wn * 64 +  0 + lr) * 64 + gx);
    bfr1 = *(const bf16x8*)(Bcur + (wn * 64 + 16 + lr) * 64 + gx);
    if (notlast) STAGE_A(0, Anxt, kt + 1);
    __builtin_amdgcn_s_barrier();
    asm volatile("s_waitcnt lgkmcnt(0)" ::: "memory");
    __builtin_amdgcn_sched_barrier(0);
    __builtin_amdgcn_s_setprio(1);
    #pragma unroll
    for (int mf = 0; mf < 8; ++mf) {
      acc[mf][0] = mfma16(af[mf], bfr0, acc[mf][0]);
      acc[mf][1] = mfma16(af[mf], bfr1, acc[mf][1]);
    }
    __builtin_amdgcn_s_setprio(0);
    __builtin_amdgcn_s_barrier();

    // ---- phase 1: ks=0, qn=1 (reuse af); stage Bh0(t+1)
    bfr0 = *(const bf16x8*)(Bcur + (wn * 64 + 32 + lr) * 64 + gx);
    bfr1 = *(const bf16x8*)(Bcur + (wn * 64 + 48 + lr) * 64 + gx);
    if (notlast) STAGE_B(0, Bnxt, kt + 1);
    __builtin_amdgcn_s_barrier();
    asm volatile("s_waitcnt lgkmcnt(0)" ::: "memory");
    __builtin_amdgcn_sched_barrier(0);
    __builtin_amdgcn_s_setprio(1);
    #pragma unroll
    for (int mf = 0; mf < 8; ++mf) {
      acc[mf][2] = mfma16(af[mf], bfr0, acc[mf][2]);
      acc[mf][3] = mfma16(af[mf], bfr1, acc[mf][3]);
    }
    __builtin_amdgcn_s_setprio(0);
    // gate Ah1,Bh1(cur): retire own oldest 4 BEFORE the barrier; P2 reads after
    if (notlast) { asm volatile("s_waitcnt vmcnt(4)" ::: "memory"); }
    else         { asm volatile("s_waitcnt vmcnt(0)" ::: "memory"); }
    __builtin_amdgcn_s_barrier();

    // ---- phase 2: ks=1, qn=0; stage Ah1(t+1)
    #pragma unroll
    for (int mf = 0; mf < 8; ++mf)
      af[mf] = *(const bf16x8*)(Acur + 16384 + (wm * 128 + mf * 16 + lr) * 64 + gx);
    bfr0 = *(const bf16x8*)(Bcur + 16384 + (wn * 64 +  0 + lr) * 64 + gx);
    bfr1 = *(const bf16x8*)(Bcur + 16384 + (wn * 64 + 16 + lr) * 64 + gx);
    if (notlast) STAGE_A(1, Anxt, kt + 1);
    __builtin_amdgcn_s_barrier();
    asm volatile("s_waitcnt lgkmcnt(0)" ::: "memory");
    __builtin_amdgcn_sched_barrier(0);
    __builtin_amdgcn_s_setprio(1);
    #pragma unroll
    for (int mf = 0; mf < 8; ++mf) {
      acc[mf][0] = mfma16(af[mf], bfr0, acc[mf][0]);
      acc[mf][1] = mfma16(af[mf], bfr1, acc[mf][1]);
    }
    __builtin_amdgcn_s_setprio(0);
    __builtin_amdgcn_s_barrier();

    // ---- phase 3: ks=1, qn=1 (reuse af); stage Bh1(t+1)
    bfr0 = *(const bf16x8*)(Bcur + 16384 + (wn * 64 + 32 + lr) * 64 + gx);
    bfr1 = *(const bf16x8*)(Bcur + 16384 + (wn * 64 + 48 + lr) * 64 + gx);
    if (notlast) STAGE_B(1, Bnxt, kt + 1);
    __builtin_amdgcn_s_barrier();
    asm volatile("s_waitcnt lgkmcnt(0)" ::: "memory");
    __builtin_amdgcn_sched_barrier(0);
    __builtin_amdgcn_s_setprio(1);
    #pragma unroll
    for (int mf = 0; mf < 8; ++mf) {
      acc[mf][2] = mfma16(af[mf], bfr0, acc[mf][2]);
      acc[mf][3] = mfma16(af[mf], bfr1, acc[mf][3]);
    }
    __builtin_amdgcn_s_setprio(0);
    // gate Ah0,Bh0(t+1): retire own oldest 4 BEFORE the barrier; next-iter P0
    // reads after. (Last iter: trivially satisfied, nothing outstanding.)
    asm volatile("s_waitcnt vmcnt(4)" ::: "memory");
    __builtin_amdgcn_s_barrier();
  }

  // ---- epilogue ----
  int tsel = 0;
  const float* bsel = b0;
  if constexpr (OUT_MODE == 0) {
    tsel = nbase >> 11;
    bsel = (tsel == 0) ? b0 : ((tsel == 1) ? b1 : b2);
  }
  #pragma unroll
  for (int j = 0; j < 4; ++j) {
    int n = nbase + wn * 64 + j * 16 + lr;
    float bv = (OUT_MODE == 0) ? bsel[n & 2047] : bsel[n];
    #pragma unroll
    for (int mf = 0; mf < 8; ++mf) {
      #pragma unroll
      for (int r = 0; r < 4; ++r) {
        int m = mbase + wm * 128 + mf * 16 + g * 4 + r;
        float val = acc[mf][j][r] + bv;
        if constexpr (OUT_MODE == 0) {
          int b = m >> 11, s = m & 2047, nn = n & 2047, h = nn >> 7, d = nn & 127;
          ((bf16*)Cout)[(size_t)tsel * ((size_t)Mn * En) +
                        ((size_t)(b * Hn + h) * Sn + s) * Dn + d] = (bf16)val;
        } else {
          ((float*)Cout)[(size_t)m * N + n] = val;
        }
      }
    }
  }
}

// ---------------- Flash attention (unchanged; vmcnt/lgkmcnt already precede
// the barrier, so the cross-wave staging invariant holds here) ----------------
__global__ __launch_bounds__(256, 2) void attn(
    const bf16* __restrict__ Q, const bf16* __restrict__ K,
    const bf16* __restrict__ Vt, bf16* __restrict__ O)
{
  __shared__ __align__(16) uint8_t smem[65536];
  const int tid = threadIdx.x, lane = tid & 63, w = tid >> 6;
  const int g = lane >> 4, lr = lane & 15;
  const int lid = blockIdx.x + (int)gridDim.x * blockIdx.y;
  const int xcd = lid & 7, j = lid >> 3;
  const int bh = xcd * 8 + (j >> 4);
  const int q0 = (j & 15) * 128;
  const size_t hoff = (size_t)bh * Sn * Dn;
  const bf16* Qh = Q + hoff;
  const bf16* Kh = K + hoff;
  const bf16* Vh = Vt + hoff;   // [D][S]
  const float SC2 = 0.12751744f; // 1/sqrt(128) * log2(e)

  #pragma unroll
  for (int it = 0; it < 8; ++it) {
    int cl = it * 256 + tid;
    int row = cl >> 4, cs = cl & 15;
    int cg = cs ^ (row & 7);
    gload16(Qh + (size_t)(q0 + row) * Dn + cg * 8, smem + (it * 256 + (tid & ~63)) * 16);
  }
  __syncthreads();
  bf16x8 qf[2][4];
  #pragma unroll
  for (int nf = 0; nf < 2; ++nf)
    #pragma unroll
    for (int ks = 0; ks < 4; ++ks) {
      int row = w * 32 + nf * 16 + lr;
      qf[nf][ks] = *(const bf16x8*)(smem + row * 256 + (((ks * 4 + g) ^ (row & 7)) << 4));
    }
  __syncthreads();

  const int vd = tid >> 1, vhw = tid & 1;
  const bf16* vrow = Vh + (size_t)vd * Sn + vhw * 32;

  uint4 vr0, vr1, vr2, vr3;
  #pragma unroll
  for (int it = 0; it < 4; ++it) {
    int cl = it * 256 + tid;
    int row = cl >> 4, cs = cl & 15;
    int cg = cs ^ (row & 7);
    gload16(Kh + (size_t)row * Dn + cg * 8, smem + (it * 256 + (tid & ~63)) * 16);
  }
  { const uint4* vs = (const uint4*)vrow;
    vr0 = vs[0]; vr1 = vs[1]; vr2 = vs[2]; vr3 = vs[3]; }

  f32x4 o[2][8] = {};
  float m2[2] = { -__builtin_inff(), -__builtin_inff() };
  float lrun[2] = { 0.f, 0.f };

  for (int t = 0; t < 32; ++t) {
    const int cur = t & 1;
    uint8_t* Kcur = smem + (cur << 14);
    uint8_t* Knxt = smem + ((cur ^ 1) << 14);
    uint8_t* Vcur = smem + 32768 + (cur << 14);
    asm volatile("s_waitcnt vmcnt(0)" ::: "memory");
    {
      uint8_t* base = Vcur + vd * 128;
      const int sw = vd & 7, cb = vhw * 4;
      *(uint4*)(base + (((cb + 0) ^ sw) << 4)) = make_uint4(vr0.x, vr0.y, vr2.x, vr2.y);
      *(uint4*)(base + (((cb + 1) ^ sw) << 4)) = make_uint4(vr0.z, vr0.w, vr2.z, vr2.w);
      *(uint4*)(base + (((cb + 2) ^ sw) << 4)) = make_uint4(vr1.x, vr1.y, vr3.x, vr3.y);
      *(uint4*)(base + (((cb + 3) ^ sw) << 4)) = make_uint4(vr1.z, vr1.w, vr3.z, vr3.w);
    }
    if (t < 31) {
      const int kvn = (t + 1) * 64;
      #pragma unroll
      for (int it = 0; it < 4; ++it) {
        int cl = it * 256 + tid;
        int row = cl >> 4, cs = cl & 15;
        int cg = cs ^ (row & 7);
        gload16(Kh + (size_t)(kvn + row) * Dn + cg * 8,
                Knxt + (it * 256 + (tid & ~63)) * 16);
      }
      const uint4* vs = (const uint4*)(vrow + kvn);
      vr0 = vs[0]; vr1 = vs[1]; vr2 = vs[2]; vr3 = vs[3];
    }
    asm volatile("s_waitcnt lgkmcnt(0)" ::: "memory");
    asm volatile("s_barrier" ::: "memory");

    f32x4 sfr[2][4] = {};
    __builtin_amdgcn_s_setprio(1);
    #pragma unroll
    for (int ks = 0; ks < 4; ++ks) {
      #pragma unroll
      for (int mf = 0; mf < 4; ++mf) {
        int row = mf * 16 + lr;
        bf16x8 kf = *(const bf16x8*)(Kcur + row * 256 + (((ks * 4 + g) ^ (row & 7)) << 4));
        sfr[0][mf] = mfma16(kf, qf[0][ks], sfr[0][mf]);
        sfr[1][mf] = mfma16(kf, qf[1][ks], sfr[1][mf]);
      }
    }
    __builtin_amdgcn_s_setprio(0);

    bf16x8 pa[2][2];
    #pragma unroll
    for (int nf = 0; nf < 2; ++nf) {
      f32x4 a0, a1;
      #pragma unroll
      for (int r = 0; r < 4; ++r) a0[r] = fmaxf(sfr[nf][0][r], sfr[nf][1][r]);
      #pragma unroll
      for (int r = 0; r < 4; ++r) a1[r] = fmaxf(sfr[nf][2][r], sfr[nf][3][r]);
      #pragma unroll
      for (int r = 0; r < 4; ++r) a0[r] = fmaxf(a0[r], a1[r]);
      float mx = fmaxf(fmaxf(a0[0], a0[1]), fmaxf(a0[2], a0[3]));
      mx = fmaxf(mx, __shfl_xor(mx, 16));
      mx = fmaxf(mx, __shfl_xor(mx, 32));
      float pm2 = mx * SC2;
      if (__any(pm2 > m2[nf] + 8.f)) {
        float mnew = fmaxf(m2[nf], pm2);
        float fsc = EXP2F(m2[nf] - mnew);
        m2[nf] = mnew;
        lrun[nf] *= fsc;
        float fv[4];
        #pragma unroll
        for (int r = 0; r < 4; ++r) fv[r] = __shfl(fsc, g * 4 + r);
        #pragma unroll
        for (int df = 0; df < 8; ++df)
          #pragma unroll
          for (int r = 0; r < 4; ++r) o[nf][df][r] *= fv[r];
      }
      const float mc = m2[nf];
      f32x4 p[4];
      #pragma unroll
      for (int mf = 0; mf < 4; ++mf)
        #pragma unroll
        for (int r = 0; r < 4; ++r)
          p[mf][r] = EXP2F(__builtin_fmaf(sfr[nf][mf][r], SC2, -mc));
      f32x4 s0, s1;
      #pragma unroll
      for (int r = 0; r < 4; ++r) s0[r] = p[0][r] + p[1][r];
      #pragma unroll
      for (int r = 0; r < 4; ++r) s1[r] = p[2][r] + p[3][r];
      #pragma unroll
      for (int r = 0; r < 4; ++r) s0[r] += s1[r];
      float ps = (s0[0] + s0[1]) + (s0[2] + s0[3]);
      ps += __shfl_xor(ps, 16);
      ps += __shfl_xor(ps, 32);
      lrun[nf] += ps;
      #pragma unroll
      for (int ks = 0; ks < 2; ++ks) {
        bf16x8 tt;
        #pragma unroll
        for (int i = 0; i < 4; ++i) {
          tt[i]     = (bf16)p[2 * ks][i];
          tt[i + 4] = (bf16)p[2 * ks + 1][i];
        }
        pa[nf][ks] = tt;
      }
    }

    __builtin_amdgcn_s_setprio(1);
    #pragma unroll
    for (int ks = 0; ks < 2; ++ks) {
      #pragma unroll
      for (int df = 0; df < 8; ++df) {
        int row = df * 16 + lr;
        bf16x8 vf = *(const bf16x8*)(Vcur + row * 128 + (((ks * 4 + g) ^ (row & 7)) << 4));
        o[0][df] = mfma16(pa[0][ks], vf, o[0][df]);
        o[1][df] = mfma16(pa[1][ks], vf, o[1][df]);
      }
    }
    __builtin_amdgcn_s_setprio(0);
    asm volatile("s_barrier" ::: "memory");
  }

  const int b = bh >> 4, h = bh & 15;
  #pragma unroll
  for (int nf = 0; nf < 2; ++nf) {
    float inv = 1.f / lrun[nf];
    float iv[4];
    #pragma unroll
    for (int r = 0; r < 4; ++r) iv[r] = __shfl(inv, g * 4 + r);
    #pragma unroll
    for (int df = 0; df < 8; ++df) {
      #pragma unroll
      for (int r = 0; r < 4; ++r) {
        int qrow = q0 + w * 32 + nf * 16 + g * 4 + r;
        int d = df * 16 + lr;
        size_t m = (size_t)b * Sn + qrow;
        O[m * En + h * Dn + d] = (bf16)(o[nf][df][r] * iv[r]);
      }
    }
  }
}

// ---------------- host ----------------
extern "C" void kernel_launch(void* const* d_in, const int* in_sizes, int n_in,
                              void* d_out, int out_size, void* d_ws, size_t ws_size,
                              hipStream_t stream) {
  const float* X  = (const float*)d_in[0];
  const float* Wq = (const float*)d_in[1];
  const float* bq = (const float*)d_in[2];
  const float* Wk = (const float*)d_in[3];
  const float* bk = (const float*)d_in[4];
  const float* Wv = (const float*)d_in[5];
  const float* bv = (const float*)d_in[6];
  const float* Wo = (const float*)d_in[7];
  const float* bo = (const float*)d_in[8];

  bf16* ws = (bf16*)d_ws;
  const size_t szE = (size_t)Mn * En;
  const size_t szW = (size_t)En * En;
  bf16* Xb  = ws;
  bf16* Wqt = Xb + szE;      // Wqt/Wkt/Wvt contiguous => fused QKV B-matrix [6144][2048]
  bf16* Wkt = Wqt + szW;
  bf16* Wvt = Wkt + szW;
  bf16* Wot = Wvt + szW;
  bf16* Qb  = Wot + szW;     // Q/K/V contiguous => tsel*szE addressing in epilogue
  bf16* Kb  = Qb + szE;
  bf16* Vb  = Kb + szE;
  bf16* Vtp = Vb + szE;
  bf16* AO  = Vb;            // alias: V consumed by vtrans before attn writes AO

  cvt_x<<<2048, 256, 0, stream>>>(X, Xb, (int)(szE / 8));
  wtrans<<<dim3(32, 32), 256, 0, stream>>>(Wq, Wqt);
  wtrans<<<dim3(32, 32), 256, 0, stream>>>(Wk, Wkt);
  wtrans<<<dim3(32, 32), 256, 0, stream>>>(Wv, Wvt);
  wtrans<<<dim3(32, 32), 256, 0, stream>>>(Wo, Wot);
  // fused QKV: M=8192, N=6144 (Q|K|V), K=2048 ; grid 768 (%8==0)
  gemm256<0><<<768, 512, 0, stream>>>(Xb, Wqt, bq, bk, bv, Qb, Mn, 3 * En, En, 24);
  vtrans<<<dim3(32, 2, 64), 256, 0, stream>>>(Vb, Vtp);
  attn<<<dim3(16, 64), 256, 0, stream>>>(Qb, Kb, Vtp, AO);
  // output projection: M=8192, N=2048 ; grid 256 (%8==0)
  gemm256<1><<<256, 512, 0, stream>>>(AO, Wot, bo, nullptr, nullptr, d_out, Mn, En, En, 8);
}